// Round 1
// baseline (937.532 us; speedup 1.0000x reference)
//
#include <hip/hip_runtime.h>
#include <math.h>

#define N_NODES 50000
#define NFEAT 256
#define NHID 64
#define HOPS 4
#define NEDGES 800000
#define GEMM_ROWS 32
#define XS_LD 264  // padded LDS row stride (floats); 264*4=1056 B, 16B-aligned rows

// ---------------------------------------------------------------------------
// GEMM: H[n][c] = sum_k x[n][k] * W[c/64][k][c%64] + b[c],  c = hop*64 + j
// One block = 32 rows x 256 cols, 256 threads (thread = column).
// x tile staged in LDS; W columns read from global (256 KB, L2-resident).
// ---------------------------------------------------------------------------
__global__ __launch_bounds__(256) void gemm_kernel(const float* __restrict__ x,
                                                   const float* __restrict__ W,
                                                   const float* __restrict__ b,
                                                   float* __restrict__ H) {
    __shared__ float xs[GEMM_ROWS][XS_LD];
    const int t = threadIdx.x;
    const int row0 = blockIdx.x * GEMM_ROWS;

    // Cooperative load: 32*256 floats = 2048 float4s, 8 per thread, coalesced.
    for (int i = t; i < GEMM_ROWS * NFEAT / 4; i += 256) {
        const int r = (i * 4) / NFEAT;
        const int k = (i * 4) % NFEAT;
        float4 v;
        if (row0 + r < N_NODES) {
            v = *(const float4*)&x[(size_t)(row0 + r) * NFEAT + k];
        } else {
            v = make_float4(0.f, 0.f, 0.f, 0.f);
        }
        *(float4*)&xs[r][k] = v;
    }
    __syncthreads();

    const int c = t;  // output column 0..255
    const int hop = c >> 6;
    const int j = c & 63;
    const float* wp = W + (size_t)hop * (NFEAT * NHID) + j;  // stride NHID per k
    const float bias = b[c];

    float acc[GEMM_ROWS];
#pragma unroll
    for (int r = 0; r < GEMM_ROWS; ++r) acc[r] = 0.f;

    for (int k = 0; k < NFEAT; k += 4) {
        const float w0 = wp[(k + 0) * NHID];
        const float w1 = wp[(k + 1) * NHID];
        const float w2 = wp[(k + 2) * NHID];
        const float w3 = wp[(k + 3) * NHID];
#pragma unroll
        for (int r = 0; r < GEMM_ROWS; ++r) {
            const float4 xv = *(const float4*)&xs[r][k];  // wave-uniform broadcast
            acc[r] = fmaf(xv.x, w0, acc[r]);
            acc[r] = fmaf(xv.y, w1, acc[r]);
            acc[r] = fmaf(xv.z, w2, acc[r]);
            acc[r] = fmaf(xv.w, w3, acc[r]);
        }
    }

    const int rmax = (N_NODES - row0 < GEMM_ROWS) ? (N_NODES - row0) : GEMM_ROWS;
    for (int r = 0; r < rmax; ++r) {
        H[(size_t)(row0 + r) * 256 + c] = acc[r] + bias;
    }
}

// ---------------------------------------------------------------------------
// Scatter: out[row*256 + hop*64 + lane] += val * H[col*256 + hop*64 + lane]
// One wave per edge (64 lanes = 64 hidden features), EPW edges per wave.
// grid = (NEDGES/(4*EPW), HOPS), block = 256 (4 waves).
// ---------------------------------------------------------------------------
#define EPW 8
__global__ __launch_bounds__(256) void scatter_kernel(const float* __restrict__ H,
                                                      const int* __restrict__ rows,
                                                      const int* __restrict__ cols,
                                                      const float* __restrict__ vals,
                                                      float* __restrict__ out) {
    const int lane = threadIdx.x & 63;
    const int wid = __builtin_amdgcn_readfirstlane(threadIdx.x >> 6);  // force SGPR
    const int hop = blockIdx.y;
    const int wave_g = blockIdx.x * 4 + wid;
    const int e0 = wave_g * EPW;
    const int base = hop * NEDGES;
    const int hoff = hop * 64 + lane;

#pragma unroll
    for (int i = 0; i < EPW; ++i) {
        const int e = e0 + i;
        const int r = rows[base + e];   // wave-uniform -> scalar load
        const int c = cols[base + e];
        const float v = vals[base + e];
        const float h = H[(size_t)c * 256 + hoff];       // 256B coalesced gather
        unsafeAtomicAdd(&out[(size_t)r * 256 + hoff], v * h);  // hw fp32 atomic
    }
}

// ---------------------------------------------------------------------------
// ELU in place: out = x > 0 ? x : exp(x)-1
// ---------------------------------------------------------------------------
__global__ __launch_bounds__(256) void elu_kernel(float* __restrict__ out, int n4) {
    const int i = blockIdx.x * 256 + threadIdx.x;
    if (i < n4) {
        float4 v = ((float4*)out)[i];
        v.x = v.x > 0.f ? v.x : expf(v.x) - 1.f;
        v.y = v.y > 0.f ? v.y : expf(v.y) - 1.f;
        v.z = v.z > 0.f ? v.z : expf(v.z) - 1.f;
        v.w = v.w > 0.f ? v.w : expf(v.w) - 1.f;
        ((float4*)out)[i] = v;
    }
}

extern "C" void kernel_launch(void* const* d_in, const int* in_sizes, int n_in,
                              void* d_out, int out_size, void* d_ws, size_t ws_size,
                              hipStream_t stream) {
    const float* x        = (const float*)d_in[0];
    const float* W        = (const float*)d_in[1];
    const float* b        = (const float*)d_in[2];
    const int*   adj_rows = (const int*)d_in[3];
    const int*   adj_cols = (const int*)d_in[4];
    const float* adj_vals = (const float*)d_in[5];
    float* out = (float*)d_out;
    float* H   = (float*)d_ws;  // 50000*256 floats = 51.2 MB scratch

    // Zero the accumulator (harness re-poisons d_out to 0xAA before every call).
    hipMemsetAsync(d_out, 0, (size_t)out_size * sizeof(float), stream);

    gemm_kernel<<<(N_NODES + GEMM_ROWS - 1) / GEMM_ROWS, 256, 0, stream>>>(x, W, b, H);

    scatter_kernel<<<dim3(NEDGES / (4 * EPW), HOPS), 256, 0, stream>>>(
        H, adj_rows, adj_cols, adj_vals, out);

    elu_kernel<<<(out_size / 4 + 255) / 256, 256, 0, stream>>>(out, out_size / 4);
}

// Round 2
// 828.680 us; speedup vs baseline: 1.1314x; 1.1314x over previous
//
#include <hip/hip_runtime.h>
#include <math.h>

#define N_NODES 50000
#define NFEAT 256
#define NHID 64
#define HOPS 4
#define NEDGES 800000
#define NBINS (HOPS * N_NODES)          // 200000 CSR bins (hop-major)
#define GEMM_ROWS 32
#define XS_LD 264

#define SCAN_ELEMS 1024                  // elems per scan block (256 thr x 4)
#define SCAN_NBLK ((NBINS + SCAN_ELEMS - 1) / SCAN_ELEMS)  // 196

// ---------------------------------------------------------------------------
// GEMM: H[n][c] = sum_k x[n][k] * W[c/64][k][c%64] + b[c]   (unchanged)
// ---------------------------------------------------------------------------
__global__ __launch_bounds__(256) void gemm_kernel(const float* __restrict__ x,
                                                   const float* __restrict__ W,
                                                   const float* __restrict__ b,
                                                   float* __restrict__ H) {
    __shared__ float xs[GEMM_ROWS][XS_LD];
    const int t = threadIdx.x;
    const int row0 = blockIdx.x * GEMM_ROWS;

    for (int i = t; i < GEMM_ROWS * NFEAT / 4; i += 256) {
        const int r = (i * 4) / NFEAT;
        const int k = (i * 4) % NFEAT;
        float4 v;
        if (row0 + r < N_NODES) {
            v = *(const float4*)&x[(size_t)(row0 + r) * NFEAT + k];
        } else {
            v = make_float4(0.f, 0.f, 0.f, 0.f);
        }
        *(float4*)&xs[r][k] = v;
    }
    __syncthreads();

    const int c = t;
    const int hop = c >> 6;
    const int j = c & 63;
    const float* wp = W + (size_t)hop * (NFEAT * NHID) + j;
    const float bias = b[c];

    float acc[GEMM_ROWS];
#pragma unroll
    for (int r = 0; r < GEMM_ROWS; ++r) acc[r] = 0.f;

    for (int k = 0; k < NFEAT; k += 4) {
        const float w0 = wp[(k + 0) * NHID];
        const float w1 = wp[(k + 1) * NHID];
        const float w2 = wp[(k + 2) * NHID];
        const float w3 = wp[(k + 3) * NHID];
#pragma unroll
        for (int r = 0; r < GEMM_ROWS; ++r) {
            const float4 xv = *(const float4*)&xs[r][k];
            acc[r] = fmaf(xv.x, w0, acc[r]);
            acc[r] = fmaf(xv.y, w1, acc[r]);
            acc[r] = fmaf(xv.z, w2, acc[r]);
            acc[r] = fmaf(xv.w, w3, acc[r]);
        }
    }

    const int rmax = (N_NODES - row0 < GEMM_ROWS) ? (N_NODES - row0) : GEMM_ROWS;
    for (int r = 0; r < rmax; ++r) {
        H[(size_t)(row0 + r) * 256 + c] = acc[r] + bias;
    }
}

// ---------------------------------------------------------------------------
// CSR build step 1: histogram of destination rows. grid=(NEDGES/256, HOPS).
// ---------------------------------------------------------------------------
__global__ __launch_bounds__(256) void hist_kernel(const int* __restrict__ rows,
                                                   int* __restrict__ counts) {
    const int e = blockIdx.x * 256 + threadIdx.x;
    const int hop = blockIdx.y;
    const int r = rows[(size_t)hop * NEDGES + e];
    atomicAdd(&counts[hop * N_NODES + r], 1);
}

// ---------------------------------------------------------------------------
// Scan step 1: per-block totals of counts (1024 elems/block).
// ---------------------------------------------------------------------------
__global__ __launch_bounds__(256) void scan1_kernel(const int* __restrict__ counts,
                                                    int* __restrict__ bsum) {
    __shared__ int s[256];
    const int t = threadIdx.x;
    const int base = blockIdx.x * SCAN_ELEMS + t * 4;
    int sum = 0;
#pragma unroll
    for (int i = 0; i < 4; ++i) {
        const int idx = base + i;
        if (idx < NBINS) sum += counts[idx];
    }
    s[t] = sum;
    __syncthreads();
    for (int off = 128; off > 0; off >>= 1) {
        if (t < off) s[t] += s[t + off];
        __syncthreads();
    }
    if (t == 0) bsum[blockIdx.x] = s[0];
}

// ---------------------------------------------------------------------------
// Scan step 2: exclusive scan of the 196 block sums (one block).
// ---------------------------------------------------------------------------
__global__ __launch_bounds__(256) void scan2_kernel(int* __restrict__ bsum,
                                                    int* __restrict__ offsets) {
    __shared__ int s[SCAN_NBLK];
    const int t = threadIdx.x;
    if (t < SCAN_NBLK) s[t] = bsum[t];
    __syncthreads();
    if (t == 0) {
        int run = 0;
        for (int i = 0; i < SCAN_NBLK; ++i) {
            const int v = s[i];
            s[i] = run;
            run += v;
        }
        offsets[NBINS] = run;  // = HOPS*NEDGES
    }
    __syncthreads();
    if (t < SCAN_NBLK) bsum[t] = s[t];
}

// ---------------------------------------------------------------------------
// Scan step 3: full exclusive scan -> offsets; also init cursor = offsets.
// ---------------------------------------------------------------------------
__global__ __launch_bounds__(256) void scan3_kernel(const int* __restrict__ counts,
                                                    const int* __restrict__ bsum,
                                                    int* __restrict__ offsets,
                                                    int* __restrict__ cursor) {
    __shared__ int s[256];
    const int t = threadIdx.x;
    const int base = blockIdx.x * SCAN_ELEMS + t * 4;
    int v[4];
    int tsum = 0;
#pragma unroll
    for (int i = 0; i < 4; ++i) {
        const int idx = base + i;
        v[i] = (idx < NBINS) ? counts[idx] : 0;
        tsum += v[i];
    }
    s[t] = tsum;
    __syncthreads();
    // Hillis-Steele inclusive scan over the 256 thread sums.
    for (int off = 1; off < 256; off <<= 1) {
        const int add = (t >= off) ? s[t - off] : 0;
        __syncthreads();
        s[t] += add;
        __syncthreads();
    }
    int run = bsum[blockIdx.x] + s[t] - tsum;  // exclusive prefix for this thread
#pragma unroll
    for (int i = 0; i < 4; ++i) {
        const int idx = base + i;
        if (idx < NBINS) {
            offsets[idx] = run;
            cursor[idx] = run;
            run += v[i];
        }
    }
}

// ---------------------------------------------------------------------------
// CSR build step 2: scatter edges into sorted order (packed {col, val}).
// ---------------------------------------------------------------------------
__global__ __launch_bounds__(256) void fill_kernel(const int* __restrict__ rows,
                                                   const int* __restrict__ cols,
                                                   const float* __restrict__ vals,
                                                   int* __restrict__ cursor,
                                                   int2* __restrict__ epk) {
    const int e = blockIdx.x * 256 + threadIdx.x;
    const int hop = blockIdx.y;
    const size_t ge = (size_t)hop * NEDGES + e;
    const int r = rows[ge];
    const int c = cols[ge];
    const float v = vals[ge];
    const int idx = atomicAdd(&cursor[hop * N_NODES + r], 1);
    epk[idx] = make_int2(c, __float_as_int(v));
}

// ---------------------------------------------------------------------------
// Gather: one block per output row; wave w handles hop w, lane = feature.
// Each out element written exactly once; ELU fused.
// ---------------------------------------------------------------------------
__global__ __launch_bounds__(256) void gather_kernel(const float* __restrict__ H,
                                                     const int* __restrict__ offsets,
                                                     const int2* __restrict__ epk,
                                                     float* __restrict__ out) {
    const int row = blockIdx.x;
    const int hop = threadIdx.x >> 6;
    const int lane = threadIdx.x & 63;
    const int bin = hop * N_NODES + row;
    const int s = offsets[bin];
    const int e2 = offsets[bin + 1];
    const int hoff = hop * 64 + lane;

    float acc0 = 0.f, acc1 = 0.f;
    int e = s;
    for (; e + 1 < e2; e += 2) {
        const int2 p0 = epk[e];        // same addr all lanes -> broadcast
        const int2 p1 = epk[e + 1];
        const float h0 = H[(size_t)p0.x * 256 + hoff];
        const float h1 = H[(size_t)p1.x * 256 + hoff];
        acc0 = fmaf(__int_as_float(p0.y), h0, acc0);
        acc1 = fmaf(__int_as_float(p1.y), h1, acc1);
    }
    if (e < e2) {
        const int2 p0 = epk[e];
        acc0 = fmaf(__int_as_float(p0.y), H[(size_t)p0.x * 256 + hoff], acc0);
    }
    float r = acc0 + acc1;
    r = r > 0.f ? r : expf(r) - 1.f;   // ELU fused
    out[(size_t)row * 256 + hoff] = r;
}

// ---------------------------------------------------------------------------
// Fallback path (atomic scatter) if workspace is too small for CSR.
// ---------------------------------------------------------------------------
#define EPW 8
__global__ __launch_bounds__(256) void scatter_kernel(const float* __restrict__ H,
                                                      const int* __restrict__ rows,
                                                      const int* __restrict__ cols,
                                                      const float* __restrict__ vals,
                                                      float* __restrict__ out) {
    const int lane = threadIdx.x & 63;
    const int wid = __builtin_amdgcn_readfirstlane(threadIdx.x >> 6);
    const int hop = blockIdx.y;
    const int e0 = (blockIdx.x * 4 + wid) * EPW;
    const int base = hop * NEDGES;
    const int hoff = hop * 64 + lane;
#pragma unroll
    for (int i = 0; i < EPW; ++i) {
        const int e = e0 + i;
        const int r = rows[base + e];
        const int c = cols[base + e];
        const float v = vals[base + e];
        unsafeAtomicAdd(&out[(size_t)r * 256 + hoff], v * H[(size_t)c * 256 + hoff]);
    }
}

__global__ __launch_bounds__(256) void elu_kernel(float* __restrict__ out, int n4) {
    const int i = blockIdx.x * 256 + threadIdx.x;
    if (i < n4) {
        float4 v = ((float4*)out)[i];
        v.x = v.x > 0.f ? v.x : expf(v.x) - 1.f;
        v.y = v.y > 0.f ? v.y : expf(v.y) - 1.f;
        v.z = v.z > 0.f ? v.z : expf(v.z) - 1.f;
        v.w = v.w > 0.f ? v.w : expf(v.w) - 1.f;
        ((float4*)out)[i] = v;
    }
}

extern "C" void kernel_launch(void* const* d_in, const int* in_sizes, int n_in,
                              void* d_out, int out_size, void* d_ws, size_t ws_size,
                              hipStream_t stream) {
    const float* x        = (const float*)d_in[0];
    const float* W        = (const float*)d_in[1];
    const float* b        = (const float*)d_in[2];
    const int*   adj_rows = (const int*)d_in[3];
    const int*   adj_cols = (const int*)d_in[4];
    const float* adj_vals = (const float*)d_in[5];
    float* out = (float*)d_out;

    // Workspace layout (256B aligned slices)
    char* w = (char*)d_ws;
    size_t off = 0;
    float* H = (float*)(w + off);      off += (size_t)N_NODES * 256 * 4;      // 51.2 MB
    int* counts  = (int*)(w + off);    off += (size_t)NBINS * 4;              // 800 KB
    int* offsets = (int*)(w + off);    off += ((size_t)(NBINS + 1) * 4 + 255) & ~255ull;
    int* cursor  = (int*)(w + off);    off += (size_t)NBINS * 4;
    int* bsum    = (int*)(w + off);    off += ((size_t)SCAN_NBLK * 4 + 255) & ~255ull;
    int2* epk    = (int2*)(w + off);   off += (size_t)HOPS * NEDGES * 8;      // 25.6 MB
    const bool use_csr = (ws_size >= off);

    gemm_kernel<<<(N_NODES + GEMM_ROWS - 1) / GEMM_ROWS, 256, 0, stream>>>(x, W, b, H);

    if (use_csr) {
        hipMemsetAsync(counts, 0, (size_t)NBINS * 4, stream);
        hist_kernel<<<dim3(NEDGES / 256, HOPS), 256, 0, stream>>>(adj_rows, counts);
        scan1_kernel<<<SCAN_NBLK, 256, 0, stream>>>(counts, bsum);
        scan2_kernel<<<1, 256, 0, stream>>>(bsum, offsets);
        scan3_kernel<<<SCAN_NBLK, 256, 0, stream>>>(counts, bsum, offsets, cursor);
        fill_kernel<<<dim3(NEDGES / 256, HOPS), 256, 0, stream>>>(adj_rows, adj_cols,
                                                                  adj_vals, cursor, epk);
        gather_kernel<<<N_NODES, 256, 0, stream>>>(H, offsets, epk, out);
    } else {
        hipMemsetAsync(d_out, 0, (size_t)out_size * sizeof(float), stream);
        scatter_kernel<<<dim3(NEDGES / (4 * EPW), HOPS), 256, 0, stream>>>(
            H, adj_rows, adj_cols, adj_vals, out);
        elu_kernel<<<(out_size / 4 + 255) / 256, 256, 0, stream>>>(out, out_size / 4);
    }
}

// Round 3
// 545.061 us; speedup vs baseline: 1.7201x; 1.5203x over previous
//
#include <hip/hip_runtime.h>
#include <math.h>

#define N_NODES 50000
#define NFEAT 256
#define NHID 64
#define HOPS 4
#define NEDGES 800000
#define NBINS (HOPS * N_NODES)      // 200000 per-(hop,row) bins
#define GEMM_ROWS 32
#define XS_LD 264

#define BROWS 256                    // rows per coarse bucket
#define NBUCK 196                    // ceil(50000/256) buckets per hop
#define NBK_ALL (HOPS * NBUCK)       // 784
#define CHUNK 8192                   // edges per partition block
#define NCHUNK ((NEDGES + CHUNK - 1) / CHUNK)  // 98
#define FS_CAP 8192                  // LDS edge capacity in fine sort (mean 4082 + 64 sigma)

// ---------------------------------------------------------------------------
// GEMM: H[n][c] = sum_k x[n][k] * W[c/64][k][c%64] + b[c]   (unchanged)
// ---------------------------------------------------------------------------
__global__ __launch_bounds__(256) void gemm_kernel(const float* __restrict__ x,
                                                   const float* __restrict__ W,
                                                   const float* __restrict__ b,
                                                   float* __restrict__ H) {
    __shared__ float xs[GEMM_ROWS][XS_LD];
    const int t = threadIdx.x;
    const int row0 = blockIdx.x * GEMM_ROWS;

    for (int i = t; i < GEMM_ROWS * NFEAT / 4; i += 256) {
        const int r = (i * 4) / NFEAT;
        const int k = (i * 4) % NFEAT;
        float4 v;
        if (row0 + r < N_NODES) {
            v = *(const float4*)&x[(size_t)(row0 + r) * NFEAT + k];
        } else {
            v = make_float4(0.f, 0.f, 0.f, 0.f);
        }
        *(float4*)&xs[r][k] = v;
    }
    __syncthreads();

    const int c = t;
    const int hop = c >> 6;
    const int j = c & 63;
    const float* wp = W + (size_t)hop * (NFEAT * NHID) + j;
    const float bias = b[c];

    float acc[GEMM_ROWS];
#pragma unroll
    for (int r = 0; r < GEMM_ROWS; ++r) acc[r] = 0.f;

    for (int k = 0; k < NFEAT; k += 4) {
        const float w0 = wp[(k + 0) * NHID];
        const float w1 = wp[(k + 1) * NHID];
        const float w2 = wp[(k + 2) * NHID];
        const float w3 = wp[(k + 3) * NHID];
#pragma unroll
        for (int r = 0; r < GEMM_ROWS; ++r) {
            const float4 xv = *(const float4*)&xs[r][k];
            acc[r] = fmaf(xv.x, w0, acc[r]);
            acc[r] = fmaf(xv.y, w1, acc[r]);
            acc[r] = fmaf(xv.z, w2, acc[r]);
            acc[r] = fmaf(xv.w, w3, acc[r]);
        }
    }

    const int rmax = (N_NODES - row0 < GEMM_ROWS) ? (N_NODES - row0) : GEMM_ROWS;
    for (int r = 0; r < rmax; ++r) {
        H[(size_t)(row0 + r) * 256 + c] = acc[r] + bias;
    }
}

// ---------------------------------------------------------------------------
// Coarse-bucket histogram: LDS per-block hist -> few global atomics.
// grid = (NCHUNK, HOPS)
// ---------------------------------------------------------------------------
__global__ __launch_bounds__(256) void bhist_kernel(const int* __restrict__ rows,
                                                    int* __restrict__ bucket_cnt) {
    __shared__ int h[NBUCK];
    const int t = threadIdx.x;
    for (int i = t; i < NBUCK; i += 256) h[i] = 0;
    __syncthreads();
    const int hop = blockIdx.y;
    const int e0 = blockIdx.x * CHUNK;
    const int n = min(CHUNK, NEDGES - e0);
    const size_t base = (size_t)hop * NEDGES + e0;
    for (int i = t; i < n; i += 256) {
        atomicAdd(&h[rows[base + i] >> 8], 1);
    }
    __syncthreads();
    for (int i = t; i < NBUCK; i += 256) {
        if (h[i]) atomicAdd(&bucket_cnt[hop * NBUCK + i], h[i]);
    }
}

// ---------------------------------------------------------------------------
// Exclusive scan of the 784 bucket counts (one block). Sets claim cursors
// and the offsets sentinel.
// ---------------------------------------------------------------------------
__global__ __launch_bounds__(256) void bscan_kernel(const int* __restrict__ cnt,
                                                    int* __restrict__ start,
                                                    int* __restrict__ cursor,
                                                    int* __restrict__ offsets) {
    __shared__ int s[256];
    const int t = threadIdx.x;
    int v[4];
    int tsum = 0;
#pragma unroll
    for (int i = 0; i < 4; ++i) {
        const int idx = t * 4 + i;
        v[i] = (idx < NBK_ALL) ? cnt[idx] : 0;
        tsum += v[i];
    }
    s[t] = tsum;
    __syncthreads();
    for (int off = 1; off < 256; off <<= 1) {
        const int a = (t >= off) ? s[t - off] : 0;
        __syncthreads();
        s[t] += a;
        __syncthreads();
    }
    int run = s[t] - tsum;
#pragma unroll
    for (int i = 0; i < 4; ++i) {
        const int idx = t * 4 + i;
        if (idx < NBK_ALL) {
            start[idx] = run;
            cursor[idx] = run;
            run += v[i];
        }
    }
    if (t == 255) {
        start[NBK_ALL] = run;          // = HOPS*NEDGES
        offsets[NBINS] = run;          // gather sentinel
    }
}

// ---------------------------------------------------------------------------
// Coarse partition: per-block counting sort of an 8192-edge chunk in LDS,
// flushed as contiguous runs per bucket (streaming full-line writes).
// Payload: {(row<<16)|col, float_bits(val)}. grid = (NCHUNK, HOPS)
// ---------------------------------------------------------------------------
__global__ __launch_bounds__(256) void partition_kernel(const int* __restrict__ rows,
                                                        const int* __restrict__ cols,
                                                        const float* __restrict__ vals,
                                                        int* __restrict__ cursor,
                                                        int2* __restrict__ partbuf) {
    __shared__ int2 pay[CHUNK];                     // 64 KB
    __shared__ int h[NBUCK], excl[NBUCK], gbase[NBUCK], lcur[NBUCK];
    __shared__ int s[256];
    const int t = threadIdx.x;
    const int hop = blockIdx.y;
    const int e0 = blockIdx.x * CHUNK;
    const int n = min(CHUNK, NEDGES - e0);
    const size_t base = (size_t)hop * NEDGES + e0;

    for (int i = t; i < NBUCK; i += 256) h[i] = 0;
    __syncthreads();

    int myrow[CHUNK / 256];
#pragma unroll
    for (int j = 0; j < CHUNK / 256; ++j) {
        const int i = t + j * 256;
        if (i < n) {
            const int r = rows[base + i];
            myrow[j] = r;
            atomicAdd(&h[r >> 8], 1);
        }
    }
    __syncthreads();

    // exclusive scan of h (196 padded to 256) + global cursor claim
    const int hv = (t < NBUCK) ? h[t] : 0;
    s[t] = hv;
    __syncthreads();
    for (int off = 1; off < 256; off <<= 1) {
        const int a = (t >= off) ? s[t - off] : 0;
        __syncthreads();
        s[t] += a;
        __syncthreads();
    }
    if (t < NBUCK) {
        const int ex = s[t] - hv;
        excl[t] = ex;
        lcur[t] = ex;
        gbase[t] = hv ? atomicAdd(&cursor[hop * NBUCK + t], hv) : 0;
    }
    __syncthreads();

    // scatter into LDS ordered by bucket
#pragma unroll
    for (int j = 0; j < CHUNK / 256; ++j) {
        const int i = t + j * 256;
        if (i < n) {
            const int r = myrow[j];
            const int c = cols[base + i];
            const float v = vals[base + i];
            const int pos = atomicAdd(&lcur[r >> 8], 1);
            pay[pos] = make_int2((r << 16) | c, __float_as_int(v));
        }
    }
    __syncthreads();

    // flush: consecutive LDS slots are bucket-ordered -> coalesced runs
    for (int i = t; i < n; i += 256) {
        const int2 p = pay[i];
        const int bk = ((unsigned)p.x) >> 24;       // (row>>16)>>8
        partbuf[gbase[bk] + (i - excl[bk])] = p;
    }
}

// ---------------------------------------------------------------------------
// Fine sort within each bucket, IN PLACE (bucket window is L2-hot).
// Emits per-row offsets and repacks payload to {col, val}.
// grid = (NBUCK, HOPS)
// ---------------------------------------------------------------------------
__global__ __launch_bounds__(256) void fsort_kernel(const int* __restrict__ start,
                                                    int2* __restrict__ partbuf,
                                                    int* __restrict__ offsets) {
    __shared__ int2 pay[FS_CAP];                    // 64 KB
    __shared__ int h[BROWS], excl[BROWS], cur[BROWS];
    __shared__ int s[256];
    const int t = threadIdx.x;
    const int hop = blockIdx.y;
    const int bucket = blockIdx.x;
    const int g = hop * NBUCK + bucket;
    const int s0 = start[g];
    const int n = min(start[g + 1] - s0, FS_CAP);

    h[t] = 0;
    __syncthreads();

    for (int i = t; i < n; i += 256) {
        const int2 p = partbuf[s0 + i];
        pay[i] = p;
        atomicAdd(&h[((unsigned)p.x >> 16) & 255], 1);
    }
    __syncthreads();

    const int hv = h[t];
    s[t] = hv;
    __syncthreads();
    for (int off = 1; off < 256; off <<= 1) {
        const int a = (t >= off) ? s[t - off] : 0;
        __syncthreads();
        s[t] += a;
        __syncthreads();
    }
    const int ex = s[t] - hv;
    excl[t] = ex;
    cur[t] = 0;
    const int row = bucket * BROWS + t;
    if (row < N_NODES) offsets[hop * N_NODES + row] = s0 + ex;
    __syncthreads();

    for (int i = t; i < n; i += 256) {
        const int2 p = pay[i];
        const int rl = ((unsigned)p.x >> 16) & 255;
        const int pos = s0 + excl[rl] + atomicAdd(&cur[rl], 1);
        partbuf[pos] = make_int2(p.x & 0xFFFF, p.y);   // {col, val}
    }
}

// ---------------------------------------------------------------------------
// Gather: one block per row; wave w = hop w, lane = feature. ELU fused.
// ---------------------------------------------------------------------------
__global__ __launch_bounds__(256) void gather_kernel(const float* __restrict__ H,
                                                     const int* __restrict__ offsets,
                                                     const int2* __restrict__ epk,
                                                     float* __restrict__ out) {
    const int row = blockIdx.x;
    const int hop = threadIdx.x >> 6;
    const int lane = threadIdx.x & 63;
    const int bin = hop * N_NODES + row;
    const int s = offsets[bin];
    const int e2 = offsets[bin + 1];
    const int hoff = hop * 64 + lane;

    float acc0 = 0.f, acc1 = 0.f;
    int e = s;
    for (; e + 1 < e2; e += 2) {
        const int2 p0 = epk[e];
        const int2 p1 = epk[e + 1];
        const float h0 = H[(size_t)p0.x * 256 + hoff];
        const float h1 = H[(size_t)p1.x * 256 + hoff];
        acc0 = fmaf(__int_as_float(p0.y), h0, acc0);
        acc1 = fmaf(__int_as_float(p1.y), h1, acc1);
    }
    if (e < e2) {
        const int2 p0 = epk[e];
        acc0 = fmaf(__int_as_float(p0.y), H[(size_t)p0.x * 256 + hoff], acc0);
    }
    float r = acc0 + acc1;
    r = r > 0.f ? r : expf(r) - 1.f;
    out[(size_t)row * 256 + hoff] = r;
}

// ---------------------------------------------------------------------------
// Fallback path (atomic scatter) if workspace is too small.
// ---------------------------------------------------------------------------
#define EPW 8
__global__ __launch_bounds__(256) void scatter_kernel(const float* __restrict__ H,
                                                      const int* __restrict__ rows,
                                                      const int* __restrict__ cols,
                                                      const float* __restrict__ vals,
                                                      float* __restrict__ out) {
    const int lane = threadIdx.x & 63;
    const int wid = __builtin_amdgcn_readfirstlane(threadIdx.x >> 6);
    const int hop = blockIdx.y;
    const int e0 = (blockIdx.x * 4 + wid) * EPW;
    const int base = hop * NEDGES;
    const int hoff = hop * 64 + lane;
#pragma unroll
    for (int i = 0; i < EPW; ++i) {
        const int e = e0 + i;
        const int r = rows[base + e];
        const int c = cols[base + e];
        const float v = vals[base + e];
        unsafeAtomicAdd(&out[(size_t)r * 256 + hoff], v * H[(size_t)c * 256 + hoff]);
    }
}

__global__ __launch_bounds__(256) void elu_kernel(float* __restrict__ out, int n4) {
    const int i = blockIdx.x * 256 + threadIdx.x;
    if (i < n4) {
        float4 v = ((float4*)out)[i];
        v.x = v.x > 0.f ? v.x : expf(v.x) - 1.f;
        v.y = v.y > 0.f ? v.y : expf(v.y) - 1.f;
        v.z = v.z > 0.f ? v.z : expf(v.z) - 1.f;
        v.w = v.w > 0.f ? v.w : expf(v.w) - 1.f;
        ((float4*)out)[i] = v;
    }
}

extern "C" void kernel_launch(void* const* d_in, const int* in_sizes, int n_in,
                              void* d_out, int out_size, void* d_ws, size_t ws_size,
                              hipStream_t stream) {
    const float* x        = (const float*)d_in[0];
    const float* W        = (const float*)d_in[1];
    const float* b        = (const float*)d_in[2];
    const int*   adj_rows = (const int*)d_in[3];
    const int*   adj_cols = (const int*)d_in[4];
    const float* adj_vals = (const float*)d_in[5];
    float* out = (float*)d_out;

    // Workspace layout (~77.7 MB total; round 2 proved >= 79.3 MB available)
    char* w = (char*)d_ws;
    size_t off = 0;
    float* H          = (float*)(w + off); off += (size_t)N_NODES * 256 * 4;            // 51.2 MB
    int2*  partbuf    = (int2*)(w + off);  off += (size_t)HOPS * NEDGES * 8;            // 25.6 MB
    int*   offsets    = (int*)(w + off);   off += (((size_t)(NBINS + 1)) * 4 + 255) & ~255ull;
    int*   bucket_cnt = (int*)(w + off);   off += ((size_t)NBK_ALL * 4 + 255) & ~255ull;
    int*   bstart     = (int*)(w + off);   off += (((size_t)NBK_ALL + 1) * 4 + 255) & ~255ull;
    int*   bcursor    = (int*)(w + off);   off += ((size_t)NBK_ALL * 4 + 255) & ~255ull;
    const bool use_sorted = (ws_size >= off);

    gemm_kernel<<<(N_NODES + GEMM_ROWS - 1) / GEMM_ROWS, 256, 0, stream>>>(x, W, b, H);

    if (use_sorted) {
        hipMemsetAsync(bucket_cnt, 0, (size_t)NBK_ALL * 4, stream);
        bhist_kernel<<<dim3(NCHUNK, HOPS), 256, 0, stream>>>(adj_rows, bucket_cnt);
        bscan_kernel<<<1, 256, 0, stream>>>(bucket_cnt, bstart, bcursor, offsets);
        partition_kernel<<<dim3(NCHUNK, HOPS), 256, 0, stream>>>(adj_rows, adj_cols,
                                                                 adj_vals, bcursor, partbuf);
        fsort_kernel<<<dim3(NBUCK, HOPS), 256, 0, stream>>>(bstart, partbuf, offsets);
        gather_kernel<<<N_NODES, 256, 0, stream>>>(H, offsets, partbuf, out);
    } else {
        hipMemsetAsync(d_out, 0, (size_t)out_size * sizeof(float), stream);
        scatter_kernel<<<dim3(NEDGES / (4 * EPW), HOPS), 256, 0, stream>>>(
            H, adj_rows, adj_cols, adj_vals, out);
        elu_kernel<<<(out_size / 4 + 255) / 256, 256, 0, stream>>>(out, out_size / 4);
    }
}

// Round 4
// 482.520 us; speedup vs baseline: 1.9430x; 1.1296x over previous
//
#include <hip/hip_runtime.h>
#include <hip/hip_bf16.h>
#include <math.h>

#define N_NODES 50000
#define NFEAT 256
#define NHID 64
#define HOPS 4
#define NEDGES 800000
#define NBINS (HOPS * N_NODES)      // 200000 per-(hop,row) bins
#define GEMM_ROWS 32
#define XS_LD 264

#define BROWS 256                    // rows per coarse bucket
#define NBUCK 196                    // ceil(50000/256) buckets per hop
#define NBK_ALL (HOPS * NBUCK)       // 784
#define CHUNK 8192                   // edges per partition block
#define NCHUNK ((NEDGES + CHUNK - 1) / CHUNK)  // 98
#define FS_CAP 8192                  // LDS edge capacity in fine sort

// ---------------------------------------------------------------------------
// GEMM: H[n][c] = bf16( sum_k x[n][k] * W[c/64][k][c%64] + b[c] )
// ---------------------------------------------------------------------------
__global__ __launch_bounds__(256) void gemm_kernel(const float* __restrict__ x,
                                                   const float* __restrict__ W,
                                                   const float* __restrict__ b,
                                                   __hip_bfloat16* __restrict__ H) {
    __shared__ float xs[GEMM_ROWS][XS_LD];
    const int t = threadIdx.x;
    const int row0 = blockIdx.x * GEMM_ROWS;

    for (int i = t; i < GEMM_ROWS * NFEAT / 4; i += 256) {
        const int r = (i * 4) / NFEAT;
        const int k = (i * 4) % NFEAT;
        float4 v;
        if (row0 + r < N_NODES) {
            v = *(const float4*)&x[(size_t)(row0 + r) * NFEAT + k];
        } else {
            v = make_float4(0.f, 0.f, 0.f, 0.f);
        }
        *(float4*)&xs[r][k] = v;
    }
    __syncthreads();

    const int c = t;
    const int hop = c >> 6;
    const int j = c & 63;
    const float* wp = W + (size_t)hop * (NFEAT * NHID) + j;
    const float bias = b[c];

    float acc[GEMM_ROWS];
#pragma unroll
    for (int r = 0; r < GEMM_ROWS; ++r) acc[r] = 0.f;

    for (int k = 0; k < NFEAT; k += 4) {
        const float w0 = wp[(k + 0) * NHID];
        const float w1 = wp[(k + 1) * NHID];
        const float w2 = wp[(k + 2) * NHID];
        const float w3 = wp[(k + 3) * NHID];
#pragma unroll
        for (int r = 0; r < GEMM_ROWS; ++r) {
            const float4 xv = *(const float4*)&xs[r][k];
            acc[r] = fmaf(xv.x, w0, acc[r]);
            acc[r] = fmaf(xv.y, w1, acc[r]);
            acc[r] = fmaf(xv.z, w2, acc[r]);
            acc[r] = fmaf(xv.w, w3, acc[r]);
        }
    }

    const int rmax = (N_NODES - row0 < GEMM_ROWS) ? (N_NODES - row0) : GEMM_ROWS;
    for (int r = 0; r < rmax; ++r) {
        H[(size_t)(row0 + r) * 256 + c] = __float2bfloat16(acc[r] + bias);
    }
}

// ---------------------------------------------------------------------------
// Coarse-bucket histogram. grid = (NCHUNK, HOPS)
// ---------------------------------------------------------------------------
__global__ __launch_bounds__(256) void bhist_kernel(const int* __restrict__ rows,
                                                    int* __restrict__ bucket_cnt) {
    __shared__ int h[NBUCK];
    const int t = threadIdx.x;
    for (int i = t; i < NBUCK; i += 256) h[i] = 0;
    __syncthreads();
    const int hop = blockIdx.y;
    const int e0 = blockIdx.x * CHUNK;
    const int n = min(CHUNK, NEDGES - e0);
    const size_t base = (size_t)hop * NEDGES + e0;
    for (int i = t; i < n; i += 256) {
        atomicAdd(&h[rows[base + i] >> 8], 1);
    }
    __syncthreads();
    for (int i = t; i < NBUCK; i += 256) {
        if (h[i]) atomicAdd(&bucket_cnt[hop * NBUCK + i], h[i]);
    }
}

// ---------------------------------------------------------------------------
// Exclusive scan of the 784 bucket counts (one block).
// ---------------------------------------------------------------------------
__global__ __launch_bounds__(256) void bscan_kernel(const int* __restrict__ cnt,
                                                    int* __restrict__ start,
                                                    int* __restrict__ cursor,
                                                    int* __restrict__ offsets) {
    __shared__ int s[256];
    const int t = threadIdx.x;
    int v[4];
    int tsum = 0;
#pragma unroll
    for (int i = 0; i < 4; ++i) {
        const int idx = t * 4 + i;
        v[i] = (idx < NBK_ALL) ? cnt[idx] : 0;
        tsum += v[i];
    }
    s[t] = tsum;
    __syncthreads();
    for (int off = 1; off < 256; off <<= 1) {
        const int a = (t >= off) ? s[t - off] : 0;
        __syncthreads();
        s[t] += a;
        __syncthreads();
    }
    int run = s[t] - tsum;
#pragma unroll
    for (int i = 0; i < 4; ++i) {
        const int idx = t * 4 + i;
        if (idx < NBK_ALL) {
            start[idx] = run;
            cursor[idx] = run;
            run += v[i];
        }
    }
    if (t == 255) {
        start[NBK_ALL] = run;
        offsets[NBINS] = run;
    }
}

// ---------------------------------------------------------------------------
// Coarse partition into 256-row buckets via LDS counting sort.
// Payload: {(row<<16)|col, float_bits(val)}. grid = (NCHUNK, HOPS)
// ---------------------------------------------------------------------------
__global__ __launch_bounds__(256) void partition_kernel(const int* __restrict__ rows,
                                                        const int* __restrict__ cols,
                                                        const float* __restrict__ vals,
                                                        int* __restrict__ cursor,
                                                        int2* __restrict__ partbuf) {
    __shared__ int2 pay[CHUNK];                     // 64 KB
    __shared__ int h[NBUCK], excl[NBUCK], gbase[NBUCK], lcur[NBUCK];
    __shared__ int s[256];
    const int t = threadIdx.x;
    const int hop = blockIdx.y;
    const int e0 = blockIdx.x * CHUNK;
    const int n = min(CHUNK, NEDGES - e0);
    const size_t base = (size_t)hop * NEDGES + e0;

    for (int i = t; i < NBUCK; i += 256) h[i] = 0;
    __syncthreads();

    int myrow[CHUNK / 256];
#pragma unroll
    for (int j = 0; j < CHUNK / 256; ++j) {
        const int i = t + j * 256;
        if (i < n) {
            const int r = rows[base + i];
            myrow[j] = r;
            atomicAdd(&h[r >> 8], 1);
        }
    }
    __syncthreads();

    const int hv = (t < NBUCK) ? h[t] : 0;
    s[t] = hv;
    __syncthreads();
    for (int off = 1; off < 256; off <<= 1) {
        const int a = (t >= off) ? s[t - off] : 0;
        __syncthreads();
        s[t] += a;
        __syncthreads();
    }
    if (t < NBUCK) {
        const int ex = s[t] - hv;
        excl[t] = ex;
        lcur[t] = ex;
        gbase[t] = hv ? atomicAdd(&cursor[hop * NBUCK + t], hv) : 0;
    }
    __syncthreads();

#pragma unroll
    for (int j = 0; j < CHUNK / 256; ++j) {
        const int i = t + j * 256;
        if (i < n) {
            const int r = myrow[j];
            const int c = cols[base + i];
            const float v = vals[base + i];
            const int pos = atomicAdd(&lcur[r >> 8], 1);
            pay[pos] = make_int2((r << 16) | c, __float_as_int(v));
        }
    }
    __syncthreads();

    for (int i = t; i < n; i += 256) {
        const int2 p = pay[i];
        const int bk = ((unsigned)p.x) >> 24;
        partbuf[gbase[bk] + (i - excl[bk])] = p;
    }
}

// ---------------------------------------------------------------------------
// Fine sort within each bucket, in place; emits per-row offsets, repacks
// payload to {col, val}. grid = (NBUCK, HOPS)
// ---------------------------------------------------------------------------
__global__ __launch_bounds__(256) void fsort_kernel(const int* __restrict__ start,
                                                    int2* __restrict__ partbuf,
                                                    int* __restrict__ offsets) {
    __shared__ int2 pay[FS_CAP];                    // 64 KB
    __shared__ int h[BROWS], excl[BROWS], cur[BROWS];
    __shared__ int s[256];
    const int t = threadIdx.x;
    const int hop = blockIdx.y;
    const int bucket = blockIdx.x;
    const int g = hop * NBUCK + bucket;
    const int s0 = start[g];
    const int n = min(start[g + 1] - s0, FS_CAP);

    h[t] = 0;
    __syncthreads();

    for (int i = t; i < n; i += 256) {
        const int2 p = partbuf[s0 + i];
        pay[i] = p;
        atomicAdd(&h[((unsigned)p.x >> 16) & 255], 1);
    }
    __syncthreads();

    const int hv = h[t];
    s[t] = hv;
    __syncthreads();
    for (int off = 1; off < 256; off <<= 1) {
        const int a = (t >= off) ? s[t - off] : 0;
        __syncthreads();
        s[t] += a;
        __syncthreads();
    }
    const int ex = s[t] - hv;
    excl[t] = ex;
    cur[t] = 0;
    const int row = bucket * BROWS + t;
    if (row < N_NODES) offsets[hop * N_NODES + row] = s0 + ex;
    __syncthreads();

    for (int i = t; i < n; i += 256) {
        const int2 p = pay[i];
        const int rl = ((unsigned)p.x >> 16) & 255;
        const int pos = s0 + excl[rl] + atomicAdd(&cur[rl], 1);
        partbuf[pos] = make_int2(p.x & 0xFFFF, p.y);   // {col, val}
    }
}

// ---------------------------------------------------------------------------
// Gather (bf16 H): one block per row; wave w = hop w, lane = feature.
// 4-deep unrolled for MLP. ELU fused.
// ---------------------------------------------------------------------------
__global__ __launch_bounds__(256) void gather_kernel(const __hip_bfloat16* __restrict__ H,
                                                     const int* __restrict__ offsets,
                                                     const int2* __restrict__ epk,
                                                     float* __restrict__ out) {
    const int row = blockIdx.x;
    const int hop = threadIdx.x >> 6;
    const int lane = threadIdx.x & 63;
    const int bin = hop * N_NODES + row;
    const int s = offsets[bin];
    const int e2 = offsets[bin + 1];
    const int hoff = hop * 64 + lane;

    float acc0 = 0.f, acc1 = 0.f, acc2 = 0.f, acc3 = 0.f;
    int e = s;
    for (; e + 3 < e2; e += 4) {
        const int2 p0 = epk[e];
        const int2 p1 = epk[e + 1];
        const int2 p2 = epk[e + 2];
        const int2 p3 = epk[e + 3];
        const float h0 = __bfloat162float(H[(size_t)p0.x * 256 + hoff]);
        const float h1 = __bfloat162float(H[(size_t)p1.x * 256 + hoff]);
        const float h2 = __bfloat162float(H[(size_t)p2.x * 256 + hoff]);
        const float h3 = __bfloat162float(H[(size_t)p3.x * 256 + hoff]);
        acc0 = fmaf(__int_as_float(p0.y), h0, acc0);
        acc1 = fmaf(__int_as_float(p1.y), h1, acc1);
        acc2 = fmaf(__int_as_float(p2.y), h2, acc2);
        acc3 = fmaf(__int_as_float(p3.y), h3, acc3);
    }
    for (; e < e2; ++e) {
        const int2 p0 = epk[e];
        acc0 = fmaf(__int_as_float(p0.y),
                    __bfloat162float(H[(size_t)p0.x * 256 + hoff]), acc0);
    }
    float r = (acc0 + acc1) + (acc2 + acc3);
    r = r > 0.f ? r : expf(r) - 1.f;
    out[(size_t)row * 256 + hoff] = r;
}

// ---------------------------------------------------------------------------
// Fallback path (atomic scatter) if workspace is too small.
// ---------------------------------------------------------------------------
#define EPW 8
__global__ __launch_bounds__(256) void scatter_kernel(const __hip_bfloat16* __restrict__ H,
                                                      const int* __restrict__ rows,
                                                      const int* __restrict__ cols,
                                                      const float* __restrict__ vals,
                                                      float* __restrict__ out) {
    const int lane = threadIdx.x & 63;
    const int wid = __builtin_amdgcn_readfirstlane(threadIdx.x >> 6);
    const int hop = blockIdx.y;
    const int e0 = (blockIdx.x * 4 + wid) * EPW;
    const int base = hop * NEDGES;
    const int hoff = hop * 64 + lane;
#pragma unroll
    for (int i = 0; i < EPW; ++i) {
        const int e = e0 + i;
        const int r = rows[base + e];
        const int c = cols[base + e];
        const float v = vals[base + e];
        unsafeAtomicAdd(&out[(size_t)r * 256 + hoff],
                        v * __bfloat162float(H[(size_t)c * 256 + hoff]));
    }
}

__global__ __launch_bounds__(256) void elu_kernel(float* __restrict__ out, int n4) {
    const int i = blockIdx.x * 256 + threadIdx.x;
    if (i < n4) {
        float4 v = ((float4*)out)[i];
        v.x = v.x > 0.f ? v.x : expf(v.x) - 1.f;
        v.y = v.y > 0.f ? v.y : expf(v.y) - 1.f;
        v.z = v.z > 0.f ? v.z : expf(v.z) - 1.f;
        v.w = v.w > 0.f ? v.w : expf(v.w) - 1.f;
        ((float4*)out)[i] = v;
    }
}

extern "C" void kernel_launch(void* const* d_in, const int* in_sizes, int n_in,
                              void* d_out, int out_size, void* d_ws, size_t ws_size,
                              hipStream_t stream) {
    const float* x        = (const float*)d_in[0];
    const float* W        = (const float*)d_in[1];
    const float* b        = (const float*)d_in[2];
    const int*   adj_rows = (const int*)d_in[3];
    const int*   adj_cols = (const int*)d_in[4];
    const float* adj_vals = (const float*)d_in[5];
    float* out = (float*)d_out;

    // Workspace layout (~52 MB total)
    char* w = (char*)d_ws;
    size_t off = 0;
    __hip_bfloat16* H = (__hip_bfloat16*)(w + off);
    off += (size_t)N_NODES * 256 * 2;                                          // 25.6 MB
    int2*  partbuf    = (int2*)(w + off);  off += (size_t)HOPS * NEDGES * 8;   // 25.6 MB
    int*   offsets    = (int*)(w + off);   off += (((size_t)(NBINS + 1)) * 4 + 255) & ~255ull;
    int*   bucket_cnt = (int*)(w + off);   off += ((size_t)NBK_ALL * 4 + 255) & ~255ull;
    int*   bstart     = (int*)(w + off);   off += (((size_t)NBK_ALL + 1) * 4 + 255) & ~255ull;
    int*   bcursor    = (int*)(w + off);   off += ((size_t)NBK_ALL * 4 + 255) & ~255ull;
    const bool use_sorted = (ws_size >= off);

    gemm_kernel<<<(N_NODES + GEMM_ROWS - 1) / GEMM_ROWS, 256, 0, stream>>>(x, W, b, H);

    if (use_sorted) {
        hipMemsetAsync(bucket_cnt, 0, (size_t)NBK_ALL * 4, stream);
        bhist_kernel<<<dim3(NCHUNK, HOPS), 256, 0, stream>>>(adj_rows, bucket_cnt);
        bscan_kernel<<<1, 256, 0, stream>>>(bucket_cnt, bstart, bcursor, offsets);
        partition_kernel<<<dim3(NCHUNK, HOPS), 256, 0, stream>>>(adj_rows, adj_cols,
                                                                 adj_vals, bcursor, partbuf);
        fsort_kernel<<<dim3(NBUCK, HOPS), 256, 0, stream>>>(bstart, partbuf, offsets);
        gather_kernel<<<N_NODES, 256, 0, stream>>>(H, offsets, partbuf, out);
    } else {
        hipMemsetAsync(d_out, 0, (size_t)out_size * sizeof(float), stream);
        scatter_kernel<<<dim3(NEDGES / (4 * EPW), HOPS), 256, 0, stream>>>(
            H, adj_rows, adj_cols, adj_vals, out);
        elu_kernel<<<(out_size / 4 + 255) / 256, 256, 0, stream>>>(out, out_size / 4);
    }
}

// Round 5
// 414.275 us; speedup vs baseline: 2.2631x; 1.1647x over previous
//
#include <hip/hip_runtime.h>
#include <hip/hip_bf16.h>
#include <math.h>

#define N_NODES 50000
#define NFEAT 256
#define NHID 64
#define HOPS 4
#define NEDGES 800000
#define NBINS (HOPS * N_NODES)      // 200000 per-(hop,row) bins

#define BROWS 256                    // rows per coarse bucket
#define NBUCK 196                    // ceil(50000/256) buckets per hop
#define NBK_ALL (HOPS * NBUCK)       // 784
#define CHUNK 8192                   // edges per partition block
#define NCHUNK ((NEDGES + CHUNK - 1) / CHUNK)  // 98
#define FS_CAP 8192                  // LDS edge capacity in fine sort

// MFMA GEMM tile config
#define GM 64                        // rows per block
#define LDP 40                       // LDS k-stride in bf16 (80 B: 16B-aligned, 2-way banks)
#define NGBLK ((N_NODES + GM - 1) / GM)   // 782

typedef short bf16x8 __attribute__((ext_vector_type(8)));
typedef float f32x4 __attribute__((ext_vector_type(4)));

static __device__ __forceinline__ unsigned short f2bf(float f) {
    __hip_bfloat16 h = __float2bfloat16(f);
    return *reinterpret_cast<unsigned short*>(&h);
}

// ---------------------------------------------------------------------------
// MFMA GEMM: H[n][c] = bf16( sum_k x[n][k]*Wcat[k][c] + b[c] ),
// Wcat[k][c] = W[c>>6][k][c&63].  Block: 64 rows x 256 cols, 4 waves;
// wave w covers cols [w*64, w*64+64) as 4x4 tiles of 16x16x32 MFMA.
// Verified layouts (m89): A[m=lane&15][k=quad*8+j], B[n=lane&15][k=quad*8+j],
// C/D: col=lane&15, row=quad*4+reg.
// ---------------------------------------------------------------------------
__global__ __launch_bounds__(256) void gemm_mfma_kernel(const float* __restrict__ x,
                                                        const float* __restrict__ W,
                                                        const float* __restrict__ b,
                                                        __hip_bfloat16* __restrict__ H) {
    __shared__ unsigned short A_lds[GM * LDP];     // 5120 B
    __shared__ unsigned short B_lds[256 * LDP];    // 20480 B

    const int t = threadIdx.x;
    const int lane = t & 63;
    const int w = t >> 6;              // wave id 0..3
    const int quad = lane >> 4;
    const int m16 = lane & 15;
    const int row0 = blockIdx.x * GM;

    f32x4 acc[4][4];
#pragma unroll
    for (int mt = 0; mt < 4; ++mt)
#pragma unroll
        for (int nt = 0; nt < 4; ++nt) acc[mt][nt] = (f32x4){0.f, 0.f, 0.f, 0.f};

    for (int ks = 0; ks < 8; ++ks) {
        const int k0 = ks * 32;
        // Stage A: 64 rows x 32 k, fp32 -> bf16. 512 float4s, 2/thread.
#pragma unroll
        for (int it = 0; it < 2; ++it) {
            const int i = t + it * 256;
            const int r = i >> 3;              // 0..63
            const int kq = (i & 7) * 4;        // 0,4,..28
            float4 v = make_float4(0.f, 0.f, 0.f, 0.f);
            if (row0 + r < N_NODES)
                v = *(const float4*)&x[(size_t)(row0 + r) * NFEAT + k0 + kq];
            unsigned short* d = &A_lds[r * LDP + kq];
            d[0] = f2bf(v.x); d[1] = f2bf(v.y); d[2] = f2bf(v.z); d[3] = f2bf(v.w);
        }
        // Stage B: 32 k x 256 n, fp32 -> bf16, layout [n][k]. 2048 float4s, 8/thread.
#pragma unroll
        for (int it = 0; it < 8; ++it) {
            const int i = t + it * 256;
            const int n4 = i & 63;             // n = n4*4
            const int kk = i >> 6;             // 0..31
            const int hop = n4 >> 4;
            const int j = (n4 & 15) * 4;
            const float4 v = *(const float4*)&W[(size_t)hop * (NFEAT * NHID)
                                                + (size_t)(k0 + kk) * NHID + j];
            B_lds[(n4 * 4 + 0) * LDP + kk] = f2bf(v.x);
            B_lds[(n4 * 4 + 1) * LDP + kk] = f2bf(v.y);
            B_lds[(n4 * 4 + 2) * LDP + kk] = f2bf(v.z);
            B_lds[(n4 * 4 + 3) * LDP + kk] = f2bf(v.w);
        }
        __syncthreads();

        bf16x8 af[4], bf[4];
#pragma unroll
        for (int mt = 0; mt < 4; ++mt)
            af[mt] = *(const bf16x8*)&A_lds[(mt * 16 + m16) * LDP + quad * 8];
#pragma unroll
        for (int nt = 0; nt < 4; ++nt)
            bf[nt] = *(const bf16x8*)&B_lds[(w * 64 + nt * 16 + m16) * LDP + quad * 8];
#pragma unroll
        for (int mt = 0; mt < 4; ++mt)
#pragma unroll
            for (int nt = 0; nt < 4; ++nt)
                acc[mt][nt] = __builtin_amdgcn_mfma_f32_16x16x32_bf16(
                    af[mt], bf[nt], acc[mt][nt], 0, 0, 0);
        __syncthreads();
    }

    // Epilogue: + bias, -> bf16 H. C/D: col=lane&15, row=quad*4+reg.
#pragma unroll
    for (int nt = 0; nt < 4; ++nt) {
        const int col = w * 64 + nt * 16 + m16;
        const float bias = b[col];
#pragma unroll
        for (int mt = 0; mt < 4; ++mt) {
#pragma unroll
            for (int r = 0; r < 4; ++r) {
                const int row = row0 + mt * 16 + quad * 4 + r;
                if (row < N_NODES)
                    H[(size_t)row * 256 + col] = __float2bfloat16(acc[mt][nt][r] + bias);
            }
        }
    }
}

// ---------------------------------------------------------------------------
// Coarse-bucket histogram. grid = (NCHUNK, HOPS)
// ---------------------------------------------------------------------------
__global__ __launch_bounds__(256) void bhist_kernel(const int* __restrict__ rows,
                                                    int* __restrict__ bucket_cnt) {
    __shared__ int h[NBUCK];
    const int t = threadIdx.x;
    for (int i = t; i < NBUCK; i += 256) h[i] = 0;
    __syncthreads();
    const int hop = blockIdx.y;
    const int e0 = blockIdx.x * CHUNK;
    const int n = min(CHUNK, NEDGES - e0);
    const size_t base = (size_t)hop * NEDGES + e0;
    for (int i = t; i < n; i += 256) {
        atomicAdd(&h[rows[base + i] >> 8], 1);
    }
    __syncthreads();
    for (int i = t; i < NBUCK; i += 256) {
        if (h[i]) atomicAdd(&bucket_cnt[hop * NBUCK + i], h[i]);
    }
}

// ---------------------------------------------------------------------------
// Exclusive scan of the 784 bucket counts (one block).
// ---------------------------------------------------------------------------
__global__ __launch_bounds__(256) void bscan_kernel(const int* __restrict__ cnt,
                                                    int* __restrict__ start,
                                                    int* __restrict__ cursor,
                                                    int* __restrict__ offsets) {
    __shared__ int s[256];
    const int t = threadIdx.x;
    int v[4];
    int tsum = 0;
#pragma unroll
    for (int i = 0; i < 4; ++i) {
        const int idx = t * 4 + i;
        v[i] = (idx < NBK_ALL) ? cnt[idx] : 0;
        tsum += v[i];
    }
    s[t] = tsum;
    __syncthreads();
    for (int off = 1; off < 256; off <<= 1) {
        const int a = (t >= off) ? s[t - off] : 0;
        __syncthreads();
        s[t] += a;
        __syncthreads();
    }
    int run = s[t] - tsum;
#pragma unroll
    for (int i = 0; i < 4; ++i) {
        const int idx = t * 4 + i;
        if (idx < NBK_ALL) {
            start[idx] = run;
            cursor[idx] = run;
            run += v[i];
        }
    }
    if (t == 255) {
        start[NBK_ALL] = run;
        offsets[NBINS] = run;
    }
}

// ---------------------------------------------------------------------------
// Coarse partition into 256-row buckets via LDS counting sort.
// Payload: {(row<<16)|col, float_bits(val)}. grid = (NCHUNK, HOPS)
// ---------------------------------------------------------------------------
__global__ __launch_bounds__(256) void partition_kernel(const int* __restrict__ rows,
                                                        const int* __restrict__ cols,
                                                        const float* __restrict__ vals,
                                                        int* __restrict__ cursor,
                                                        int2* __restrict__ partbuf) {
    __shared__ int2 pay[CHUNK];                     // 64 KB
    __shared__ int h[NBUCK], excl[NBUCK], gbase[NBUCK], lcur[NBUCK];
    __shared__ int s[256];
    const int t = threadIdx.x;
    const int hop = blockIdx.y;
    const int e0 = blockIdx.x * CHUNK;
    const int n = min(CHUNK, NEDGES - e0);
    const size_t base = (size_t)hop * NEDGES + e0;

    for (int i = t; i < NBUCK; i += 256) h[i] = 0;
    __syncthreads();

    int myrow[CHUNK / 256];
#pragma unroll
    for (int j = 0; j < CHUNK / 256; ++j) {
        const int i = t + j * 256;
        if (i < n) {
            const int r = rows[base + i];
            myrow[j] = r;
            atomicAdd(&h[r >> 8], 1);
        }
    }
    __syncthreads();

    const int hv = (t < NBUCK) ? h[t] : 0;
    s[t] = hv;
    __syncthreads();
    for (int off = 1; off < 256; off <<= 1) {
        const int a = (t >= off) ? s[t - off] : 0;
        __syncthreads();
        s[t] += a;
        __syncthreads();
    }
    if (t < NBUCK) {
        const int ex = s[t] - hv;
        excl[t] = ex;
        lcur[t] = ex;
        gbase[t] = hv ? atomicAdd(&cursor[hop * NBUCK + t], hv) : 0;
    }
    __syncthreads();

#pragma unroll
    for (int j = 0; j < CHUNK / 256; ++j) {
        const int i = t + j * 256;
        if (i < n) {
            const int r = myrow[j];
            const int c = cols[base + i];
            const float v = vals[base + i];
            const int pos = atomicAdd(&lcur[r >> 8], 1);
            pay[pos] = make_int2((r << 16) | c, __float_as_int(v));
        }
    }
    __syncthreads();

    for (int i = t; i < n; i += 256) {
        const int2 p = pay[i];
        const int bk = ((unsigned)p.x) >> 24;
        partbuf[gbase[bk] + (i - excl[bk])] = p;
    }
}

// ---------------------------------------------------------------------------
// Fine sort within each bucket, in place; emits per-row offsets, repacks
// payload to {col, val}. grid = (NBUCK, HOPS)
// ---------------------------------------------------------------------------
__global__ __launch_bounds__(256) void fsort_kernel(const int* __restrict__ start,
                                                    int2* __restrict__ partbuf,
                                                    int* __restrict__ offsets) {
    __shared__ int2 pay[FS_CAP];                    // 64 KB
    __shared__ int h[BROWS], excl[BROWS], cur[BROWS];
    __shared__ int s[256];
    const int t = threadIdx.x;
    const int hop = blockIdx.y;
    const int bucket = blockIdx.x;
    const int g = hop * NBUCK + bucket;
    const int s0 = start[g];
    const int n = min(start[g + 1] - s0, FS_CAP);

    h[t] = 0;
    __syncthreads();

    for (int i = t; i < n; i += 256) {
        const int2 p = partbuf[s0 + i];
        pay[i] = p;
        atomicAdd(&h[((unsigned)p.x >> 16) & 255], 1);
    }
    __syncthreads();

    const int hv = h[t];
    s[t] = hv;
    __syncthreads();
    for (int off = 1; off < 256; off <<= 1) {
        const int a = (t >= off) ? s[t - off] : 0;
        __syncthreads();
        s[t] += a;
        __syncthreads();
    }
    const int ex = s[t] - hv;
    excl[t] = ex;
    cur[t] = 0;
    const int row = bucket * BROWS + t;
    if (row < N_NODES) offsets[hop * N_NODES + row] = s0 + ex;
    __syncthreads();

    for (int i = t; i < n; i += 256) {
        const int2 p = pay[i];
        const int rl = ((unsigned)p.x >> 16) & 255;
        const int pos = s0 + excl[rl] + atomicAdd(&cur[rl], 1);
        partbuf[pos] = make_int2(p.x & 0xFFFF, p.y);   // {col, val}
    }
}

// ---------------------------------------------------------------------------
// Gather (bf16 H): one block per row; wave w = hop w, lane = feature.
// ---------------------------------------------------------------------------
__global__ __launch_bounds__(256) void gather_kernel(const __hip_bfloat16* __restrict__ H,
                                                     const int* __restrict__ offsets,
                                                     const int2* __restrict__ epk,
                                                     float* __restrict__ out) {
    const int row = blockIdx.x;
    const int hop = threadIdx.x >> 6;
    const int lane = threadIdx.x & 63;
    const int bin = hop * N_NODES + row;
    const int s = offsets[bin];
    const int e2 = offsets[bin + 1];
    const int hoff = hop * 64 + lane;

    float acc0 = 0.f, acc1 = 0.f, acc2 = 0.f, acc3 = 0.f;
    int e = s;
    for (; e + 3 < e2; e += 4) {
        const int2 p0 = epk[e];
        const int2 p1 = epk[e + 1];
        const int2 p2 = epk[e + 2];
        const int2 p3 = epk[e + 3];
        const float h0 = __bfloat162float(H[(size_t)p0.x * 256 + hoff]);
        const float h1 = __bfloat162float(H[(size_t)p1.x * 256 + hoff]);
        const float h2 = __bfloat162float(H[(size_t)p2.x * 256 + hoff]);
        const float h3 = __bfloat162float(H[(size_t)p3.x * 256 + hoff]);
        acc0 = fmaf(__int_as_float(p0.y), h0, acc0);
        acc1 = fmaf(__int_as_float(p1.y), h1, acc1);
        acc2 = fmaf(__int_as_float(p2.y), h2, acc2);
        acc3 = fmaf(__int_as_float(p3.y), h3, acc3);
    }
    for (; e < e2; ++e) {
        const int2 p0 = epk[e];
        acc0 = fmaf(__int_as_float(p0.y),
                    __bfloat162float(H[(size_t)p0.x * 256 + hoff]), acc0);
    }
    float r = (acc0 + acc1) + (acc2 + acc3);
    r = r > 0.f ? r : expf(r) - 1.f;
    out[(size_t)row * 256 + hoff] = r;
}

// ---------------------------------------------------------------------------
// Fallback path (atomic scatter) if workspace is too small.
// ---------------------------------------------------------------------------
#define EPW 8
__global__ __launch_bounds__(256) void scatter_kernel(const __hip_bfloat16* __restrict__ H,
                                                      const int* __restrict__ rows,
                                                      const int* __restrict__ cols,
                                                      const float* __restrict__ vals,
                                                      float* __restrict__ out) {
    const int lane = threadIdx.x & 63;
    const int wid = __builtin_amdgcn_readfirstlane(threadIdx.x >> 6);
    const int hop = blockIdx.y;
    const int e0 = (blockIdx.x * 4 + wid) * EPW;
    const int base = hop * NEDGES;
    const int hoff = hop * 64 + lane;
#pragma unroll
    for (int i = 0; i < EPW; ++i) {
        const int e = e0 + i;
        const int r = rows[base + e];
        const int c = cols[base + e];
        const float v = vals[base + e];
        unsafeAtomicAdd(&out[(size_t)r * 256 + hoff],
                        v * __bfloat162float(H[(size_t)c * 256 + hoff]));
    }
}

__global__ __launch_bounds__(256) void elu_kernel(float* __restrict__ out, int n4) {
    const int i = blockIdx.x * 256 + threadIdx.x;
    if (i < n4) {
        float4 v = ((float4*)out)[i];
        v.x = v.x > 0.f ? v.x : expf(v.x) - 1.f;
        v.y = v.y > 0.f ? v.y : expf(v.y) - 1.f;
        v.z = v.z > 0.f ? v.z : expf(v.z) - 1.f;
        v.w = v.w > 0.f ? v.w : expf(v.w) - 1.f;
        ((float4*)out)[i] = v;
    }
}

extern "C" void kernel_launch(void* const* d_in, const int* in_sizes, int n_in,
                              void* d_out, int out_size, void* d_ws, size_t ws_size,
                              hipStream_t stream) {
    const float* x        = (const float*)d_in[0];
    const float* W        = (const float*)d_in[1];
    const float* b        = (const float*)d_in[2];
    const int*   adj_rows = (const int*)d_in[3];
    const int*   adj_cols = (const int*)d_in[4];
    const float* adj_vals = (const float*)d_in[5];
    float* out = (float*)d_out;

    // Workspace layout (~52 MB total)
    char* w = (char*)d_ws;
    size_t off = 0;
    __hip_bfloat16* H = (__hip_bfloat16*)(w + off);
    off += (size_t)N_NODES * 256 * 2;                                          // 25.6 MB
    int2*  partbuf    = (int2*)(w + off);  off += (size_t)HOPS * NEDGES * 8;   // 25.6 MB
    int*   offsets    = (int*)(w + off);   off += (((size_t)(NBINS + 1)) * 4 + 255) & ~255ull;
    int*   bucket_cnt = (int*)(w + off);   off += ((size_t)NBK_ALL * 4 + 255) & ~255ull;
    int*   bstart     = (int*)(w + off);   off += (((size_t)NBK_ALL + 1) * 4 + 255) & ~255ull;
    int*   bcursor    = (int*)(w + off);   off += ((size_t)NBK_ALL * 4 + 255) & ~255ull;
    const bool use_sorted = (ws_size >= off);

    gemm_mfma_kernel<<<NGBLK, 256, 0, stream>>>(x, W, b, H);

    if (use_sorted) {
        hipMemsetAsync(bucket_cnt, 0, (size_t)NBK_ALL * 4, stream);
        bhist_kernel<<<dim3(NCHUNK, HOPS), 256, 0, stream>>>(adj_rows, bucket_cnt);
        bscan_kernel<<<1, 256, 0, stream>>>(bucket_cnt, bstart, bcursor, offsets);
        partition_kernel<<<dim3(NCHUNK, HOPS), 256, 0, stream>>>(adj_rows, adj_cols,
                                                                 adj_vals, bcursor, partbuf);
        fsort_kernel<<<dim3(NBUCK, HOPS), 256, 0, stream>>>(bstart, partbuf, offsets);
        gather_kernel<<<N_NODES, 256, 0, stream>>>(H, offsets, partbuf, out);
    } else {
        hipMemsetAsync(d_out, 0, (size_t)out_size * sizeof(float), stream);
        scatter_kernel<<<dim3(NEDGES / (4 * EPW), HOPS), 256, 0, stream>>>(
            H, adj_rows, adj_cols, adj_vals, out);
        elu_kernel<<<(out_size / 4 + 255) / 256, 256, 0, stream>>>(out, out_size / 4);
    }
}

// Round 6
// 367.799 us; speedup vs baseline: 2.5490x; 1.1264x over previous
//
#include <hip/hip_runtime.h>
#include <hip/hip_bf16.h>
#include <math.h>

#define N_NODES 50000
#define NFEAT 256
#define NHID 64
#define HOPS 4
#define NEDGES 800000
#define NBINS (HOPS * N_NODES)      // 200000 per-(hop,row) bins

#define BROWS 256                    // rows per coarse bucket
#define NBUCK 196                    // ceil(50000/256) buckets per hop
#define NBK_ALL (HOPS * NBUCK)       // 784
#define CHUNK 8192                   // edges per partition block
#define NCHUNK ((NEDGES + CHUNK - 1) / CHUNK)  // 98
#define FS_CAP 8192                  // LDS edge capacity in fine sort

// MFMA GEMM tile config
#define GM 64                        // rows per block
#define LDP 40                       // LDS k-stride in bf16 (80 B: 16B-aligned, 2-way banks)
#define NGBLK ((N_NODES + GM - 1) / GM)   // 782

typedef short bf16x8 __attribute__((ext_vector_type(8)));
typedef float f32x4 __attribute__((ext_vector_type(4)));

static __device__ __forceinline__ unsigned short f2bf(float f) {
    __hip_bfloat16 h = __float2bfloat16(f);
    return *reinterpret_cast<unsigned short*>(&h);
}

// ---------------------------------------------------------------------------
// MFMA GEMM: H[n][c] = bf16( sum_k x[n][k]*Wcat[k][c] + b[c] )  (unchanged)
// ---------------------------------------------------------------------------
__global__ __launch_bounds__(256) void gemm_mfma_kernel(const float* __restrict__ x,
                                                        const float* __restrict__ W,
                                                        const float* __restrict__ b,
                                                        __hip_bfloat16* __restrict__ H) {
    __shared__ unsigned short A_lds[GM * LDP];     // 5120 B
    __shared__ unsigned short B_lds[256 * LDP];    // 20480 B

    const int t = threadIdx.x;
    const int lane = t & 63;
    const int w = t >> 6;
    const int quad = lane >> 4;
    const int m16 = lane & 15;
    const int row0 = blockIdx.x * GM;

    f32x4 acc[4][4];
#pragma unroll
    for (int mt = 0; mt < 4; ++mt)
#pragma unroll
        for (int nt = 0; nt < 4; ++nt) acc[mt][nt] = (f32x4){0.f, 0.f, 0.f, 0.f};

    for (int ks = 0; ks < 8; ++ks) {
        const int k0 = ks * 32;
#pragma unroll
        for (int it = 0; it < 2; ++it) {
            const int i = t + it * 256;
            const int r = i >> 3;
            const int kq = (i & 7) * 4;
            float4 v = make_float4(0.f, 0.f, 0.f, 0.f);
            if (row0 + r < N_NODES)
                v = *(const float4*)&x[(size_t)(row0 + r) * NFEAT + k0 + kq];
            unsigned short* d = &A_lds[r * LDP + kq];
            d[0] = f2bf(v.x); d[1] = f2bf(v.y); d[2] = f2bf(v.z); d[3] = f2bf(v.w);
        }
#pragma unroll
        for (int it = 0; it < 8; ++it) {
            const int i = t + it * 256;
            const int n4 = i & 63;
            const int kk = i >> 6;
            const int hop = n4 >> 4;
            const int j = (n4 & 15) * 4;
            const float4 v = *(const float4*)&W[(size_t)hop * (NFEAT * NHID)
                                                + (size_t)(k0 + kk) * NHID + j];
            B_lds[(n4 * 4 + 0) * LDP + kk] = f2bf(v.x);
            B_lds[(n4 * 4 + 1) * LDP + kk] = f2bf(v.y);
            B_lds[(n4 * 4 + 2) * LDP + kk] = f2bf(v.z);
            B_lds[(n4 * 4 + 3) * LDP + kk] = f2bf(v.w);
        }
        __syncthreads();

        bf16x8 af[4], bf[4];
#pragma unroll
        for (int mt = 0; mt < 4; ++mt)
            af[mt] = *(const bf16x8*)&A_lds[(mt * 16 + m16) * LDP + quad * 8];
#pragma unroll
        for (int nt = 0; nt < 4; ++nt)
            bf[nt] = *(const bf16x8*)&B_lds[(w * 64 + nt * 16 + m16) * LDP + quad * 8];
#pragma unroll
        for (int mt = 0; mt < 4; ++mt)
#pragma unroll
            for (int nt = 0; nt < 4; ++nt)
                acc[mt][nt] = __builtin_amdgcn_mfma_f32_16x16x32_bf16(
                    af[mt], bf[nt], acc[mt][nt], 0, 0, 0);
        __syncthreads();
    }

#pragma unroll
    for (int nt = 0; nt < 4; ++nt) {
        const int col = w * 64 + nt * 16 + m16;
        const float bias = b[col];
#pragma unroll
        for (int mt = 0; mt < 4; ++mt) {
#pragma unroll
            for (int r = 0; r < 4; ++r) {
                const int row = row0 + mt * 16 + quad * 4 + r;
                if (row < N_NODES)
                    H[(size_t)row * 256 + col] = __float2bfloat16(acc[mt][nt][r] + bias);
            }
        }
    }
}

// ---------------------------------------------------------------------------
// Coarse-bucket histogram. grid = (NCHUNK, HOPS)
// ---------------------------------------------------------------------------
__global__ __launch_bounds__(256) void bhist_kernel(const int* __restrict__ rows,
                                                    int* __restrict__ bucket_cnt) {
    __shared__ int h[NBUCK];
    const int t = threadIdx.x;
    for (int i = t; i < NBUCK; i += 256) h[i] = 0;
    __syncthreads();
    const int hop = blockIdx.y;
    const int e0 = blockIdx.x * CHUNK;
    const int n = min(CHUNK, NEDGES - e0);
    const size_t base = (size_t)hop * NEDGES + e0;
    for (int i = t; i < n; i += 256) {
        atomicAdd(&h[rows[base + i] >> 8], 1);
    }
    __syncthreads();
    for (int i = t; i < NBUCK; i += 256) {
        if (h[i]) atomicAdd(&bucket_cnt[hop * NBUCK + i], h[i]);
    }
}

// ---------------------------------------------------------------------------
// Exclusive scan of the 784 bucket counts (one block).
// ---------------------------------------------------------------------------
__global__ __launch_bounds__(256) void bscan_kernel(const int* __restrict__ cnt,
                                                    int* __restrict__ start,
                                                    int* __restrict__ cursor,
                                                    int* __restrict__ offsets) {
    __shared__ int s[256];
    const int t = threadIdx.x;
    int v[4];
    int tsum = 0;
#pragma unroll
    for (int i = 0; i < 4; ++i) {
        const int idx = t * 4 + i;
        v[i] = (idx < NBK_ALL) ? cnt[idx] : 0;
        tsum += v[i];
    }
    s[t] = tsum;
    __syncthreads();
    for (int off = 1; off < 256; off <<= 1) {
        const int a = (t >= off) ? s[t - off] : 0;
        __syncthreads();
        s[t] += a;
        __syncthreads();
    }
    int run = s[t] - tsum;
#pragma unroll
    for (int i = 0; i < 4; ++i) {
        const int idx = t * 4 + i;
        if (idx < NBK_ALL) {
            start[idx] = run;
            cursor[idx] = run;
            run += v[i];
        }
    }
    if (t == 255) {
        start[NBK_ALL] = run;
        offsets[NBINS] = run;
    }
}

// ---------------------------------------------------------------------------
// Coarse partition into 256-row buckets via LDS counting sort.
// Payload: {(row<<16)|col, float_bits(val)}. grid = (NCHUNK, HOPS)
// ---------------------------------------------------------------------------
__global__ __launch_bounds__(256) void partition_kernel(const int* __restrict__ rows,
                                                        const int* __restrict__ cols,
                                                        const float* __restrict__ vals,
                                                        int* __restrict__ cursor,
                                                        int2* __restrict__ partbuf) {
    __shared__ int2 pay[CHUNK];                     // 64 KB
    __shared__ int h[NBUCK], excl[NBUCK], gbase[NBUCK], lcur[NBUCK];
    __shared__ int s[256];
    const int t = threadIdx.x;
    const int hop = blockIdx.y;
    const int e0 = blockIdx.x * CHUNK;
    const int n = min(CHUNK, NEDGES - e0);
    const size_t base = (size_t)hop * NEDGES + e0;

    for (int i = t; i < NBUCK; i += 256) h[i] = 0;
    __syncthreads();

    int myrow[CHUNK / 256];
#pragma unroll
    for (int j = 0; j < CHUNK / 256; ++j) {
        const int i = t + j * 256;
        if (i < n) {
            const int r = rows[base + i];
            myrow[j] = r;
            atomicAdd(&h[r >> 8], 1);
        }
    }
    __syncthreads();

    const int hv = (t < NBUCK) ? h[t] : 0;
    s[t] = hv;
    __syncthreads();
    for (int off = 1; off < 256; off <<= 1) {
        const int a = (t >= off) ? s[t - off] : 0;
        __syncthreads();
        s[t] += a;
        __syncthreads();
    }
    if (t < NBUCK) {
        const int ex = s[t] - hv;
        excl[t] = ex;
        lcur[t] = ex;
        gbase[t] = hv ? atomicAdd(&cursor[hop * NBUCK + t], hv) : 0;
    }
    __syncthreads();

#pragma unroll
    for (int j = 0; j < CHUNK / 256; ++j) {
        const int i = t + j * 256;
        if (i < n) {
            const int r = myrow[j];
            const int c = cols[base + i];
            const float v = vals[base + i];
            const int pos = atomicAdd(&lcur[r >> 8], 1);
            pay[pos] = make_int2((r << 16) | c, __float_as_int(v));
        }
    }
    __syncthreads();

    for (int i = t; i < n; i += 256) {
        const int2 p = pay[i];
        const int bk = ((unsigned)p.x) >> 24;
        partbuf[gbase[bk] + (i - excl[bk])] = p;
    }
}

// ---------------------------------------------------------------------------
// Fine sort within each bucket, in place; emits per-row offsets, repacks
// payload to {col, val}. grid = (NBUCK, HOPS)
// ---------------------------------------------------------------------------
__global__ __launch_bounds__(256) void fsort_kernel(const int* __restrict__ start,
                                                    int2* __restrict__ partbuf,
                                                    int* __restrict__ offsets) {
    __shared__ int2 pay[FS_CAP];                    // 64 KB
    __shared__ int h[BROWS], excl[BROWS], cur[BROWS];
    __shared__ int s[256];
    const int t = threadIdx.x;
    const int hop = blockIdx.y;
    const int bucket = blockIdx.x;
    const int g = hop * NBUCK + bucket;
    const int s0 = start[g];
    const int n = min(start[g + 1] - s0, FS_CAP);

    h[t] = 0;
    __syncthreads();

    for (int i = t; i < n; i += 256) {
        const int2 p = partbuf[s0 + i];
        pay[i] = p;
        atomicAdd(&h[((unsigned)p.x >> 16) & 255], 1);
    }
    __syncthreads();

    const int hv = h[t];
    s[t] = hv;
    __syncthreads();
    for (int off = 1; off < 256; off <<= 1) {
        const int a = (t >= off) ? s[t - off] : 0;
        __syncthreads();
        s[t] += a;
        __syncthreads();
    }
    const int ex = s[t] - hv;
    excl[t] = ex;
    cur[t] = 0;
    const int row = bucket * BROWS + t;
    if (row < N_NODES) offsets[hop * N_NODES + row] = s0 + ex;
    __syncthreads();

    for (int i = t; i < n; i += 256) {
        const int2 p = pay[i];
        const int rl = ((unsigned)p.x >> 16) & 255;
        const int pos = s0 + excl[rl] + atomicAdd(&cur[rl], 1);
        partbuf[pos] = make_int2(p.x & 0xFFFF, p.y);   // {col, val}
    }
}

// ---------------------------------------------------------------------------
// Gather v2: block = row, wave = hop. Lane = (e8, f8): 8 edge slots x 8
// feature octets. Each lane loads bf16x8 (16 B) of H -> 1 KiB/wave/instr =
// 8 edges per VMEM instruction. Edge metadata prefetched coalesced (64/load)
// and broadcast via shfl. 3-step shfl_xor butterfly folds edge slots.
// ---------------------------------------------------------------------------
__global__ __launch_bounds__(256) void gather_kernel(const __hip_bfloat16* __restrict__ H,
                                                     const int* __restrict__ offsets,
                                                     const int2* __restrict__ epk,
                                                     float* __restrict__ out) {
    const int row = blockIdx.x;
    const int hop = threadIdx.x >> 6;
    const int lane = threadIdx.x & 63;
    const int e8 = lane >> 3;
    const int f8 = lane & 7;
    const int bin = hop * N_NODES + row;
    const int s = offsets[bin];
    const int e2 = offsets[bin + 1];
    const char* Hb = (const char*)H;
    const int hbase = (hop << 7) + (f8 << 4);   // byte offset within H row

    float acc[8];
#pragma unroll
    for (int j = 0; j < 8; ++j) acc[j] = 0.f;

    for (int g = s; g < e2; g += 64) {
        int2 p = make_int2(0, 0);
        const int eidx = g + lane;
        if (eidx < e2) p = epk[eidx];            // coalesced; masked -> val 0
        const int nit = min(8, (e2 - g + 7) >> 3);
        for (int it = 0; it < nit; ++it) {
            const int src = it * 8 + e8;
            const int col = __shfl(p.x, src, 64);
            const float val = __int_as_float(__shfl(p.y, src, 64));
            const uint4 hv = *(const uint4*)(Hb + ((size_t)col << 9) + hbase);
            const unsigned u[4] = {hv.x, hv.y, hv.z, hv.w};
#pragma unroll
            for (int q = 0; q < 4; ++q) {
                const float lo = __uint_as_float(u[q] << 16);
                const float hi = __uint_as_float(u[q] & 0xffff0000u);
                acc[q * 2]     = fmaf(val, lo, acc[q * 2]);
                acc[q * 2 + 1] = fmaf(val, hi, acc[q * 2 + 1]);
            }
        }
    }

    // Fold the 8 edge slots: butterfly across lanes ^8, ^16, ^32.
#pragma unroll
    for (int m = 8; m <= 32; m <<= 1) {
#pragma unroll
        for (int j = 0; j < 8; ++j) acc[j] += __shfl_xor(acc[j], m, 64);
    }

    if (lane < 8) {                              // lane == f8, e8 == 0
#pragma unroll
        for (int j = 0; j < 8; ++j)
            acc[j] = acc[j] > 0.f ? acc[j] : expf(acc[j]) - 1.f;
        float4* dst = (float4*)&out[(size_t)row * 256 + hop * 64 + lane * 8];
        dst[0] = make_float4(acc[0], acc[1], acc[2], acc[3]);
        dst[1] = make_float4(acc[4], acc[5], acc[6], acc[7]);
    }
}

// ---------------------------------------------------------------------------
// Fallback path (atomic scatter) if workspace is too small.
// ---------------------------------------------------------------------------
#define EPW 8
__global__ __launch_bounds__(256) void scatter_kernel(const __hip_bfloat16* __restrict__ H,
                                                      const int* __restrict__ rows,
                                                      const int* __restrict__ cols,
                                                      const float* __restrict__ vals,
                                                      float* __restrict__ out) {
    const int lane = threadIdx.x & 63;
    const int wid = __builtin_amdgcn_readfirstlane(threadIdx.x >> 6);
    const int hop = blockIdx.y;
    const int e0 = (blockIdx.x * 4 + wid) * EPW;
    const int base = hop * NEDGES;
    const int hoff = hop * 64 + lane;
#pragma unroll
    for (int i = 0; i < EPW; ++i) {
        const int e = e0 + i;
        const int r = rows[base + e];
        const int c = cols[base + e];
        const float v = vals[base + e];
        unsafeAtomicAdd(&out[(size_t)r * 256 + hoff],
                        v * __bfloat162float(H[(size_t)c * 256 + hoff]));
    }
}

__global__ __launch_bounds__(256) void elu_kernel(float* __restrict__ out, int n4) {
    const int i = blockIdx.x * 256 + threadIdx.x;
    if (i < n4) {
        float4 v = ((float4*)out)[i];
        v.x = v.x > 0.f ? v.x : expf(v.x) - 1.f;
        v.y = v.y > 0.f ? v.y : expf(v.y) - 1.f;
        v.z = v.z > 0.f ? v.z : expf(v.z) - 1.f;
        v.w = v.w > 0.f ? v.w : expf(v.w) - 1.f;
        ((float4*)out)[i] = v;
    }
}

extern "C" void kernel_launch(void* const* d_in, const int* in_sizes, int n_in,
                              void* d_out, int out_size, void* d_ws, size_t ws_size,
                              hipStream_t stream) {
    const float* x        = (const float*)d_in[0];
    const float* W        = (const float*)d_in[1];
    const float* b        = (const float*)d_in[2];
    const int*   adj_rows = (const int*)d_in[3];
    const int*   adj_cols = (const int*)d_in[4];
    const float* adj_vals = (const float*)d_in[5];
    float* out = (float*)d_out;

    // Workspace layout (~52 MB total)
    char* w = (char*)d_ws;
    size_t off = 0;
    __hip_bfloat16* H = (__hip_bfloat16*)(w + off);
    off += (size_t)N_NODES * 256 * 2;                                          // 25.6 MB
    int2*  partbuf    = (int2*)(w + off);  off += (size_t)HOPS * NEDGES * 8;   // 25.6 MB
    int*   offsets    = (int*)(w + off);   off += (((size_t)(NBINS + 1)) * 4 + 255) & ~255ull;
    int*   bucket_cnt = (int*)(w + off);   off += ((size_t)NBK_ALL * 4 + 255) & ~255ull;
    int*   bstart     = (int*)(w + off);   off += (((size_t)NBK_ALL + 1) * 4 + 255) & ~255ull;
    int*   bcursor    = (int*)(w + off);   off += ((size_t)NBK_ALL * 4 + 255) & ~255ull;
    const bool use_sorted = (ws_size >= off);

    gemm_mfma_kernel<<<NGBLK, 256, 0, stream>>>(x, W, b, H);

    if (use_sorted) {
        hipMemsetAsync(bucket_cnt, 0, (size_t)NBK_ALL * 4, stream);
        bhist_kernel<<<dim3(NCHUNK, HOPS), 256, 0, stream>>>(adj_rows, bucket_cnt);
        bscan_kernel<<<1, 256, 0, stream>>>(bucket_cnt, bstart, bcursor, offsets);
        partition_kernel<<<dim3(NCHUNK, HOPS), 256, 0, stream>>>(adj_rows, adj_cols,
                                                                 adj_vals, bcursor, partbuf);
        fsort_kernel<<<dim3(NBUCK, HOPS), 256, 0, stream>>>(bstart, partbuf, offsets);
        gather_kernel<<<N_NODES, 256, 0, stream>>>(H, offsets, partbuf, out);
    } else {
        hipMemsetAsync(d_out, 0, (size_t)out_size * sizeof(float), stream);
        scatter_kernel<<<dim3(NEDGES / (4 * EPW), HOPS), 256, 0, stream>>>(
            H, adj_rows, adj_cols, adj_vals, out);
        elu_kernel<<<(out_size / 4 + 255) / 256, 256, 0, stream>>>(out, out_size / 4);
    }
}